// Round 1
// baseline (139.634 us; speedup 1.0000x reference)
//
#include <hip/hip_runtime.h>

#define ZC 32
#define HW 1024
#define VOCAB_MAX_BITS 0xFFFFFFFFull
#define VCHUNK 256
#define ROWS_PER_BLOCK 1024
#define TPB 256

__device__ __forceinline__ unsigned int fkey(float x) {
    unsigned int b = __float_as_uint(x);
    return (b & 0x80000000u) ? ~b : (b | 0x80000000u);
}

// Kernel A: row-normalize the codebook: e[v] = emb[v] / max(||emb[v]||, 1e-12)
__global__ void knorm(const float* __restrict__ emb, float* __restrict__ e, int V) {
    int r = blockIdx.x * blockDim.x + threadIdx.x;
    if (r >= V) return;
    const float4* src = reinterpret_cast<const float4*>(emb) + (size_t)r * 8;
    float4 v[8];
    float s = 0.f;
#pragma unroll
    for (int j = 0; j < 8; ++j) {
        v[j] = src[j];
        s += v[j].x * v[j].x + v[j].y * v[j].y + v[j].z * v[j].z + v[j].w * v[j].w;
    }
    float inv = 1.0f / fmaxf(sqrtf(s), 1e-12f);
    float4* dst = reinterpret_cast<float4*>(e) + (size_t)r * 8;
#pragma unroll
    for (int j = 0; j < 8; ++j) {
        float4 o;
        o.x = v[j].x * inv; o.y = v[j].y * inv; o.z = v[j].z * inv; o.w = v[j].w * inv;
        dst[j] = o;
    }
}

// Kernel B: partial argmax(z . e) over a 256-code chunk, 4 rows/thread.
// Winners merged with deterministic packed atomicMax (monotone float key, lowest-idx tiebreak).
__global__ __launch_bounds__(TPB, 2) void kargmax(const float* __restrict__ z,
                                                  const float* __restrict__ e,
                                                  unsigned long long* __restrict__ packed,
                                                  int V) {
    __shared__ float eL[VCHUNK * ZC];
    const int vc = blockIdx.x;   // which 256-code chunk
    const int rb = blockIdx.y;   // which batch image (1024 rows)
    const int tid = threadIdx.x;

    // stage 256 normalized codes (32 KB) into LDS, coalesced
    {
        const float4* src = reinterpret_cast<const float4*>(e + (size_t)vc * VCHUNK * ZC);
        float4* dst = reinterpret_cast<float4*>(eL);
#pragma unroll
        for (int j = 0; j < 8; ++j) dst[tid + j * TPB] = src[tid + j * TPB];
    }

    // load 4 z rows into registers: rows n = rb*1024 + 4*tid + i  (hw = 4*tid+i, b = rb)
    float zr[4][ZC];
    {
        const float* zb = z + (size_t)rb * ZC * HW + 4 * tid;
#pragma unroll
        for (int c = 0; c < ZC; ++c) {
            float4 t = *reinterpret_cast<const float4*>(zb + (size_t)c * HW);
            zr[0][c] = t.x; zr[1][c] = t.y; zr[2][c] = t.z; zr[3][c] = t.w;
        }
    }
    __syncthreads();

    float best0 = -1e38f, best1 = -1e38f, best2 = -1e38f, best3 = -1e38f;
    int bi0 = 0, bi1 = 0, bi2 = 0, bi3 = 0;
    const float4* eL4 = reinterpret_cast<const float4*>(eL);

    for (int v = 0; v < VCHUNK; ++v) {
        float a0 = 0.f, a1 = 0.f, a2 = 0.f, a3 = 0.f;
#pragma unroll
        for (int q = 0; q < 8; ++q) {
            float4 ev = eL4[v * 8 + q];
            a0 += zr[0][4 * q + 0] * ev.x + zr[0][4 * q + 1] * ev.y + zr[0][4 * q + 2] * ev.z + zr[0][4 * q + 3] * ev.w;
            a1 += zr[1][4 * q + 0] * ev.x + zr[1][4 * q + 1] * ev.y + zr[1][4 * q + 2] * ev.z + zr[1][4 * q + 3] * ev.w;
            a2 += zr[2][4 * q + 0] * ev.x + zr[2][4 * q + 1] * ev.y + zr[2][4 * q + 2] * ev.z + zr[2][4 * q + 3] * ev.w;
            a3 += zr[3][4 * q + 0] * ev.x + zr[3][4 * q + 1] * ev.y + zr[3][4 * q + 2] * ev.z + zr[3][4 * q + 3] * ev.w;
        }
        int g = vc * VCHUNK + v;
        bi0 = (a0 > best0) ? g : bi0; best0 = fmaxf(a0, best0);
        bi1 = (a1 > best1) ? g : bi1; best1 = fmaxf(a1, best1);
        bi2 = (a2 > best2) ? g : bi2; best2 = fmaxf(a2, best2);
        bi3 = (a3 > best3) ? g : bi3; best3 = fmaxf(a3, best3);
    }

    const int base = rb * ROWS_PER_BLOCK + 4 * tid;
    const unsigned int vm1 = (unsigned int)(V - 1);
    unsigned long long p0 = ((unsigned long long)fkey(best0) << 32) | (vm1 - (unsigned)bi0);
    unsigned long long p1 = ((unsigned long long)fkey(best1) << 32) | (vm1 - (unsigned)bi1);
    unsigned long long p2 = ((unsigned long long)fkey(best2) << 32) | (vm1 - (unsigned)bi2);
    unsigned long long p3 = ((unsigned long long)fkey(best3) << 32) | (vm1 - (unsigned)bi3);
    atomicMax(&packed[base + 0], p0);
    atomicMax(&packed[base + 1], p1);
    atomicMax(&packed[base + 2], p2);
    atomicMax(&packed[base + 3], p3);
}

// Kernel C: decode idx, gather normalized code, write z_q (b,c,h,w), partial loss sum per block.
__global__ void kfinal(const float* __restrict__ z, const float* __restrict__ e,
                       const unsigned long long* __restrict__ packed,
                       float* __restrict__ out, float* __restrict__ partial, int V) {
    __shared__ float red[TPB];
    int n = blockIdx.x * TPB + threadIdx.x;
    int b = n >> 10, hw = n & 1023;
    unsigned long long p = packed[n];
    int idx = (V - 1) - (int)(unsigned int)(p & 0xFFFFFFFFull);

    float zrow[ZC];
    float s = 0.f;
#pragma unroll
    for (int c = 0; c < ZC; ++c) {
        float t = z[((size_t)b * ZC + c) * HW + hw];
        zrow[c] = t;
        s += t * t;
    }
    float inv = 1.0f / fmaxf(sqrtf(s), 1e-12f);

    const float4* er = reinterpret_cast<const float4*>(e) + (size_t)idx * 8;
    float loss = 0.f;
#pragma unroll
    for (int q = 0; q < 8; ++q) {
        float4 ev = er[q];
        float d0 = ev.x - zrow[4 * q + 0] * inv;
        float d1 = ev.y - zrow[4 * q + 1] * inv;
        float d2 = ev.z - zrow[4 * q + 2] * inv;
        float d3 = ev.w - zrow[4 * q + 3] * inv;
        loss += d0 * d0 + d1 * d1 + d2 * d2 + d3 * d3;
        out[((size_t)b * ZC + (4 * q + 0)) * HW + hw] = ev.x;
        out[((size_t)b * ZC + (4 * q + 1)) * HW + hw] = ev.y;
        out[((size_t)b * ZC + (4 * q + 2)) * HW + hw] = ev.z;
        out[((size_t)b * ZC + (4 * q + 3)) * HW + hw] = ev.w;
    }

    red[threadIdx.x] = loss;
    __syncthreads();
    for (int st = TPB / 2; st > 0; st >>= 1) {
        if (threadIdx.x < st) red[threadIdx.x] += red[threadIdx.x + st];
        __syncthreads();
    }
    if (threadIdx.x == 0) partial[blockIdx.x] = red[0];
}

// Kernel D: deterministic serial sum of block partials -> vq_loss, commit_loss
__global__ void kloss(const float* __restrict__ partial, float* __restrict__ out,
                      int nblocks, int NC) {
    if (blockIdx.x == 0 && threadIdx.x == 0) {
        float s = 0.f;
        for (int i = 0; i < nblocks; ++i) s += partial[i];
        float mean = s / (float)NC;
        out[NC] = mean;           // vq_loss
        out[NC + 1] = 0.25f * mean;  // commit_loss (BETA = 0.25)
    }
}

extern "C" void kernel_launch(void* const* d_in, const int* in_sizes, int n_in,
                              void* d_out, int out_size, void* d_ws, size_t ws_size,
                              hipStream_t stream) {
    const float* z = (const float*)d_in[0];
    const float* emb = (const float*)d_in[1];
    float* out = (float*)d_out;

    const int N = in_sizes[0] / ZC;   // 16384 rows (b*h*w)
    const int V = in_sizes[1] / ZC;   // 8192 codes

    float* e = (float*)d_ws;                                                   // V*ZC f32 = 1 MB
    unsigned long long* packed =
        (unsigned long long*)((char*)d_ws + (size_t)V * ZC * sizeof(float));   // N u64 = 128 KB
    float* partial = (float*)((char*)packed + (size_t)N * sizeof(unsigned long long));

    hipMemsetAsync(packed, 0, (size_t)N * sizeof(unsigned long long), stream);
    knorm<<<(V + 255) / 256, 256, 0, stream>>>(emb, e, V);
    kargmax<<<dim3(V / VCHUNK, N / ROWS_PER_BLOCK), TPB, 0, stream>>>(z, e, packed, V);
    kfinal<<<N / TPB, TPB, 0, stream>>>(z, e, packed, out, partial, V);
    kloss<<<1, 64, 0, stream>>>(partial, out, N / TPB, N * ZC);
}

// Round 2
// 52.794 us; speedup vs baseline: 2.6449x; 2.6449x over previous
//
#include <hip/hip_runtime.h>

typedef _Float16 f16;
typedef _Float16 f16x8 __attribute__((ext_vector_type(8)));
typedef float f32x4 __attribute__((ext_vector_type(4)));

#define ZC 32
#define HW 1024
#define TPB 256
#define VCH 512           // codes per LDS chunk
#define ZROWS_BLK 256     // z-rows per block (4 waves x 4 z-tiles x 16)

__device__ __forceinline__ unsigned int fkey(float x) {
    unsigned int b = __float_as_uint(x);
    return (b & 0x80000000u) ? ~b : (b | 0x80000000u);
}

// Prep A: normalize codebook -> e (f32) and split into f16 hi/lo row-major [V][32]
__global__ void kprep_e(const float* __restrict__ emb, float* __restrict__ e,
                        f16* __restrict__ Eh, f16* __restrict__ El, int V) {
    int r = blockIdx.x * blockDim.x + threadIdx.x;
    if (r >= V) return;
    const float4* src = reinterpret_cast<const float4*>(emb) + (size_t)r * 8;
    float4 v[8];
    float s = 0.f;
#pragma unroll
    for (int j = 0; j < 8; ++j) {
        v[j] = src[j];
        s += v[j].x * v[j].x + v[j].y * v[j].y + v[j].z * v[j].z + v[j].w * v[j].w;
    }
    float inv = 1.0f / fmaxf(sqrtf(s), 1e-12f);
    float4* dst = reinterpret_cast<float4*>(e) + (size_t)r * 8;
    f16* eh = Eh + (size_t)r * ZC;
    f16* el = El + (size_t)r * ZC;
#pragma unroll
    for (int j = 0; j < 8; ++j) {
        float t0 = v[j].x * inv, t1 = v[j].y * inv, t2 = v[j].z * inv, t3 = v[j].w * inv;
        float4 o; o.x = t0; o.y = t1; o.z = t2; o.w = t3;
        dst[j] = o;
        f16 h0 = (f16)t0, h1 = (f16)t1, h2 = (f16)t2, h3 = (f16)t3;
        eh[4 * j + 0] = h0; eh[4 * j + 1] = h1; eh[4 * j + 2] = h2; eh[4 * j + 3] = h3;
        el[4 * j + 0] = (f16)(t0 - (float)h0);
        el[4 * j + 1] = (f16)(t1 - (float)h1);
        el[4 * j + 2] = (f16)(t2 - (float)h2);
        el[4 * j + 3] = (f16)(t3 - (float)h3);
    }
}

// Prep B: build B-operand fragments of Z^T in MFMA-ready layout.
// ZF[zt][lane] = 8 f16: B[k = 8*(lane>>4)+j][col = z-row = zt*16 + (lane&15)]
// z input is [B=16][C=32][HW=1024] i.e. already K-major (Z^T native).
__global__ void kprep_z(const float* __restrict__ z, f16x8* __restrict__ ZFh,
                        f16x8* __restrict__ ZFl, int N) {
    int t = blockIdx.x * blockDim.x + threadIdx.x;   // t = zt*64 + lane
    if (t >= N * 4) return;
    int lane = t & 63, zt = t >> 6;
    int n = zt * 16 + (lane & 15);
    int b = n >> 10, hw = n & 1023;
    int kb = (lane >> 4) * 8;
    f16x8 h, l;
#pragma unroll
    for (int j = 0; j < 8; ++j) {
        float v = z[((size_t)(b * ZC + kb + j)) * HW + hw];
        f16 hh = (f16)v;
        h[j] = hh;
        l[j] = (f16)(v - (float)hh);
    }
    ZFh[t] = h;
    ZFl[t] = l;
}

// Main: S^T = E . Z^T via 3-pass f16-split MFMA, fused online argmax per z-row.
// Block: 4 waves x 4 z-tiles x 16 rows = 256 z-rows vs a 512-code LDS chunk.
__global__ __launch_bounds__(TPB, 2) void kmfma(const f16x8* __restrict__ ZFh,
                                                const f16x8* __restrict__ ZFl,
                                                const uint4* __restrict__ Eh,
                                                const uint4* __restrict__ El,
                                                unsigned long long* __restrict__ packed,
                                                int Vm1) {
    __shared__ uint4 sEh[VCH * 4];   // 512 rows x 4 16B-chunks, XOR-swizzled
    __shared__ uint4 sEl[VCH * 4];
    const int tid = threadIdx.x;
    const int cb = blockIdx.x & 15;   // code chunk
    const int zb = blockIdx.x >> 4;   // z-row group

    // stage E chunk (hi+lo, 64 KB) with bank-conflict swizzle on the q slot
    {
        const uint4* gh = Eh + (size_t)cb * (VCH * 4);
        const uint4* gl = El + (size_t)cb * (VCH * 4);
#pragma unroll
        for (int i = 0; i < 8; ++i) {
            int c = tid + i * TPB;                 // linear 16B chunk id
            int r = c >> 2, q = c & 3;
            int w = (r << 2) | (q ^ ((r >> 1) & 3));
            sEh[w] = gh[c];
            sEl[w] = gl[c];
        }
    }

    const int lane = tid & 63;
    const int wv = tid >> 6;
    const int zt0 = zb * 16 + wv * 4;

    // B fragments: 4 z-tiles x (hi, lo), fixed for the whole chunk loop
    f16x8 Bh[4], Bl[4];
#pragma unroll
    for (int i = 0; i < 4; ++i) {
        Bh[i] = ZFh[(size_t)(zt0 + i) * 64 + lane];
        Bl[i] = ZFl[(size_t)(zt0 + i) * 64 + lane];
    }
    __syncthreads();

    const int r15 = lane & 15, qq = lane >> 4;
    const int laneA = (r15 << 2) | (qq ^ ((r15 >> 1) & 3));   // swizzled A-read slot

    float bv[4] = {-1e38f, -1e38f, -1e38f, -1e38f};
    int bi[4] = {0, 0, 0, 0};
    int g = cb * VCH + qq * 4;    // code id of acc reg 0 at ct=0

    for (int ct = 0; ct < VCH / 16; ++ct) {
        f16x8 Ah = *(const f16x8*)&sEh[ct * 64 + laneA];
        f16x8 Al = *(const f16x8*)&sEl[ct * 64 + laneA];
#pragma unroll
        for (int i = 0; i < 4; ++i) {
            f32x4 acc = {0.f, 0.f, 0.f, 0.f};
            acc = __builtin_amdgcn_mfma_f32_16x16x32_f16(Ah, Bh[i], acc, 0, 0, 0);
            acc = __builtin_amdgcn_mfma_f32_16x16x32_f16(Ah, Bl[i], acc, 0, 0, 0);
            acc = __builtin_amdgcn_mfma_f32_16x16x32_f16(Al, Bh[i], acc, 0, 0, 0);
#pragma unroll
            for (int r = 0; r < 4; ++r) {
                float v = acc[r];
                bool gt = v > bv[i];
                bi[i] = gt ? (g + r) : bi[i];
                bv[i] = gt ? v : bv[i];
            }
        }
        g += 16;
    }

    // merge the 4 lane-groups holding the same z-row, then one atomic per row
#pragma unroll
    for (int i = 0; i < 4; ++i) {
        unsigned long long key =
            ((unsigned long long)fkey(bv[i]) << 32) | (unsigned int)(Vm1 - bi[i]);
        unsigned long long o;
        o = __shfl_xor(key, 16); if (o > key) key = o;
        o = __shfl_xor(key, 32); if (o > key) key = o;
        if (lane < 16) atomicMax(&packed[(size_t)(zt0 + i) * 16 + r15], key);
    }
}

// Final: decode idx, gather normalized code, write z_q (b,c,h,w), partial loss per block.
__global__ void kfinal(const float* __restrict__ z, const float* __restrict__ e,
                       const unsigned long long* __restrict__ packed,
                       float* __restrict__ out, float* __restrict__ partial, int V) {
    __shared__ float red[TPB];
    int n = blockIdx.x * TPB + threadIdx.x;
    int b = n >> 10, hw = n & 1023;
    unsigned long long p = packed[n];
    int idx = (V - 1) - (int)(unsigned int)(p & 0xFFFFFFFFull);

    float zrow[ZC];
    float s = 0.f;
#pragma unroll
    for (int c = 0; c < ZC; ++c) {
        float t = z[((size_t)b * ZC + c) * HW + hw];
        zrow[c] = t;
        s += t * t;
    }
    float inv = 1.0f / fmaxf(sqrtf(s), 1e-12f);

    const float4* er = reinterpret_cast<const float4*>(e) + (size_t)idx * 8;
    float loss = 0.f;
#pragma unroll
    for (int q = 0; q < 8; ++q) {
        float4 ev = er[q];
        float d0 = ev.x - zrow[4 * q + 0] * inv;
        float d1 = ev.y - zrow[4 * q + 1] * inv;
        float d2 = ev.z - zrow[4 * q + 2] * inv;
        float d3 = ev.w - zrow[4 * q + 3] * inv;
        loss += d0 * d0 + d1 * d1 + d2 * d2 + d3 * d3;
        out[((size_t)b * ZC + (4 * q + 0)) * HW + hw] = ev.x;
        out[((size_t)b * ZC + (4 * q + 1)) * HW + hw] = ev.y;
        out[((size_t)b * ZC + (4 * q + 2)) * HW + hw] = ev.z;
        out[((size_t)b * ZC + (4 * q + 3)) * HW + hw] = ev.w;
    }

    red[threadIdx.x] = loss;
    __syncthreads();
    for (int st = TPB / 2; st > 0; st >>= 1) {
        if (threadIdx.x < st) red[threadIdx.x] += red[threadIdx.x + st];
        __syncthreads();
    }
    if (threadIdx.x == 0) partial[blockIdx.x] = red[0];
}

__global__ void kloss(const float* __restrict__ partial, float* __restrict__ out,
                      int nblocks, int NC) {
    if (blockIdx.x == 0 && threadIdx.x == 0) {
        float s = 0.f;
        for (int i = 0; i < nblocks; ++i) s += partial[i];
        float mean = s / (float)NC;
        out[NC] = mean;            // vq_loss
        out[NC + 1] = 0.25f * mean; // commit_loss
    }
}

extern "C" void kernel_launch(void* const* d_in, const int* in_sizes, int n_in,
                              void* d_out, int out_size, void* d_ws, size_t ws_size,
                              hipStream_t stream) {
    const float* z = (const float*)d_in[0];
    const float* emb = (const float*)d_in[1];
    float* out = (float*)d_out;

    const int N = in_sizes[0] / ZC;   // 16384
    const int V = in_sizes[1] / ZC;   // 8192

    // workspace layout (all 16B-aligned)
    char* ws = (char*)d_ws;
    float* e = (float*)ws;                                   // V*32 f32   = 1 MB
    f16* Eh = (f16*)(ws + (size_t)V * ZC * 4);               // V*32 f16   = 0.5 MB
    f16* El = (f16*)(ws + (size_t)V * ZC * 6);               // 0.5 MB
    f16x8* ZFh = (f16x8*)(ws + (size_t)V * ZC * 8);          // N*32 f16   = 1 MB
    f16x8* ZFl = (f16x8*)(ws + (size_t)V * ZC * 8 + (size_t)N * ZC * 2);
    unsigned long long* packed =
        (unsigned long long*)(ws + (size_t)V * ZC * 8 + (size_t)N * ZC * 4);
    float* partial = (float*)((char*)packed + (size_t)N * 8);

    hipMemsetAsync(packed, 0, (size_t)N * 8, stream);
    kprep_e<<<(V + TPB - 1) / TPB, TPB, 0, stream>>>(emb, e, Eh, El, V);
    kprep_z<<<(N * 4 + TPB - 1) / TPB, TPB, 0, stream>>>(z, ZFh, ZFl, N);
    kmfma<<<(V / VCH) * (N / ZROWS_BLK), TPB, 0, stream>>>(
        ZFh, ZFl, (const uint4*)Eh, (const uint4*)El, packed, V - 1);
    kfinal<<<N / TPB, TPB, 0, stream>>>(z, e, packed, out, partial, V);
    kloss<<<1, 64, 0, stream>>>(partial, out, N / TPB, N * ZC);
}

// Round 3
// 42.291 us; speedup vs baseline: 3.3018x; 1.2484x over previous
//
#include <hip/hip_runtime.h>

typedef _Float16 f16;
typedef _Float16 f16x8 __attribute__((ext_vector_type(8)));
typedef float f32x4 __attribute__((ext_vector_type(4)));

#define ZC 32
#define HW 1024
#define TPB 256
#define VCH 256           // codes per LDS chunk (32 KB hi+lo -> 4 blocks/CU)
#define ZROWS_BLK 256     // z-rows per block (4 waves x 4 z-tiles x 16)

__device__ __forceinline__ unsigned int fkey(float x) {
    unsigned int b = __float_as_uint(x);
    return (b & 0x80000000u) ? ~b : (b | 0x80000000u);
}

// Fused prep: (a) z -> MFMA-ready f16 hi/lo B-fragments + packed[]=0 init,
//             (b) codebook normalize -> e (f32) + f16 hi/lo rows.
__global__ void kprep(const float* __restrict__ z, const float* __restrict__ emb,
                      float* __restrict__ e, f16* __restrict__ Eh, f16* __restrict__ El,
                      f16x8* __restrict__ ZFh, f16x8* __restrict__ ZFl,
                      unsigned long long* __restrict__ packed,
                      int N, int V, int zblocks) {
    const int blk = blockIdx.x;
    if (blk < zblocks) {
        // ---- z-prep: ZF[zt][lane] = B[k = 8*(lane>>4)+j][col = zt*16 + (lane&15)]
        int t = blk * TPB + threadIdx.x;
        if (t < N * 4) {
            int lane = t & 63, zt = t >> 6;
            int n = zt * 16 + (lane & 15);
            int b = n >> 10, hw = n & 1023;
            int kb = (lane >> 4) * 8;
            f16x8 h, l;
#pragma unroll
            for (int j = 0; j < 8; ++j) {
                float v = z[((size_t)(b * ZC + kb + j)) * HW + hw];
                f16 hh = (f16)v;
                h[j] = hh;
                l[j] = (f16)(v - (float)hh);
            }
            ZFh[t] = h;
            ZFl[t] = l;
        }
        // ---- packed init (replaces hipMemsetAsync)
        int per = (N + zblocks - 1) / zblocks;   // 64
        int p0 = blk * per + threadIdx.x;
        if (threadIdx.x < per && p0 < N) packed[p0] = 0ull;
    } else {
        // ---- e-prep: normalize codebook row, split f16 hi/lo
        int r = (blk - zblocks) * TPB + threadIdx.x;
        if (r >= V) return;
        const float4* src = reinterpret_cast<const float4*>(emb) + (size_t)r * 8;
        float4 v[8];
        float s = 0.f;
#pragma unroll
        for (int j = 0; j < 8; ++j) {
            v[j] = src[j];
            s += v[j].x * v[j].x + v[j].y * v[j].y + v[j].z * v[j].z + v[j].w * v[j].w;
        }
        float inv = 1.0f / fmaxf(sqrtf(s), 1e-12f);
        float4* dst = reinterpret_cast<float4*>(e) + (size_t)r * 8;
        f16* eh = Eh + (size_t)r * ZC;
        f16* el = El + (size_t)r * ZC;
#pragma unroll
        for (int j = 0; j < 8; ++j) {
            float t0 = v[j].x * inv, t1 = v[j].y * inv, t2 = v[j].z * inv, t3 = v[j].w * inv;
            float4 o; o.x = t0; o.y = t1; o.z = t2; o.w = t3;
            dst[j] = o;
            f16 h0 = (f16)t0, h1 = (f16)t1, h2 = (f16)t2, h3 = (f16)t3;
            eh[4 * j + 0] = h0; eh[4 * j + 1] = h1; eh[4 * j + 2] = h2; eh[4 * j + 3] = h3;
            el[4 * j + 0] = (f16)(t0 - (float)h0);
            el[4 * j + 1] = (f16)(t1 - (float)h1);
            el[4 * j + 2] = (f16)(t2 - (float)h2);
            el[4 * j + 3] = (f16)(t3 - (float)h3);
        }
    }
}

// Main: S^T = E . Z^T via 3-pass f16-split MFMA, fused online argmax per z-row.
// Block: 4 waves x 4 z-tiles = 256 z-rows vs a 256-code LDS chunk (32 KB).
__global__ __launch_bounds__(TPB, 4) void kmfma(const f16x8* __restrict__ ZFh,
                                                const f16x8* __restrict__ ZFl,
                                                const uint4* __restrict__ Eh,
                                                const uint4* __restrict__ El,
                                                unsigned long long* __restrict__ packed,
                                                int Vm1) {
    __shared__ uint4 sEh[VCH * 4];   // 256 rows x 4 16B-chunks, XOR-swizzled
    __shared__ uint4 sEl[VCH * 4];
    const int tid = threadIdx.x;
    const int zb = blockIdx.x & 63;   // z-row group (consecutive blocks share cb)
    const int cb = blockIdx.x >> 6;   // code chunk

    // stage E chunk (hi+lo, 32 KB) with bank-conflict swizzle on the q slot
    {
        const uint4* gh = Eh + (size_t)cb * (VCH * 4);
        const uint4* gl = El + (size_t)cb * (VCH * 4);
#pragma unroll
        for (int i = 0; i < 4; ++i) {
            int c = tid + i * TPB;                 // linear 16B chunk id
            int r = c >> 2, q = c & 3;
            int w = (r << 2) | (q ^ ((r >> 1) & 3));
            sEh[w] = gh[c];
            sEl[w] = gl[c];
        }
    }

    const int lane = tid & 63;
    const int wv = tid >> 6;
    const int zt0 = zb * 16 + wv * 4;

    // B fragments: 4 z-tiles x (hi, lo), fixed for the whole chunk loop
    f16x8 Bh[4], Bl[4];
#pragma unroll
    for (int i = 0; i < 4; ++i) {
        Bh[i] = ZFh[(size_t)(zt0 + i) * 64 + lane];
        Bl[i] = ZFl[(size_t)(zt0 + i) * 64 + lane];
    }
    __syncthreads();

    const int r15 = lane & 15, qq = lane >> 4;
    const int laneA = (r15 << 2) | (qq ^ ((r15 >> 1) & 3));   // swizzled A-read slot

    float bv[4] = {-1e38f, -1e38f, -1e38f, -1e38f};
    int bi[4] = {0, 0, 0, 0};
    int g = cb * VCH + qq * 4;    // code id of acc reg 0 at ct=0

    for (int ct = 0; ct < VCH / 16; ++ct) {
        f16x8 Ah = *(const f16x8*)&sEh[ct * 64 + laneA];
        f16x8 Al = *(const f16x8*)&sEl[ct * 64 + laneA];
#pragma unroll
        for (int i = 0; i < 4; ++i) {
            f32x4 acc = {0.f, 0.f, 0.f, 0.f};
            acc = __builtin_amdgcn_mfma_f32_16x16x32_f16(Ah, Bh[i], acc, 0, 0, 0);
            acc = __builtin_amdgcn_mfma_f32_16x16x32_f16(Ah, Bl[i], acc, 0, 0, 0);
            acc = __builtin_amdgcn_mfma_f32_16x16x32_f16(Al, Bh[i], acc, 0, 0, 0);
#pragma unroll
            for (int r = 0; r < 4; ++r) {
                float v = acc[r];
                bool gt = v > bv[i];
                bi[i] = gt ? (g + r) : bi[i];
                bv[i] = gt ? v : bv[i];
            }
        }
        g += 16;
    }

    // merge the 4 lane-groups holding the same z-row, then one atomic per row
#pragma unroll
    for (int i = 0; i < 4; ++i) {
        unsigned long long key =
            ((unsigned long long)fkey(bv[i]) << 32) | (unsigned int)(Vm1 - bi[i]);
        unsigned long long o;
        o = __shfl_xor(key, 16); if (o > key) key = o;
        o = __shfl_xor(key, 32); if (o > key) key = o;
        if (lane < 16) atomicMax(&packed[(size_t)(zt0 + i) * 16 + r15], key);
    }
}

// Final: decode idx, gather normalized code, write z_q (b,c,h,w), partial loss per block.
__global__ void kfinal(const float* __restrict__ z, const float* __restrict__ e,
                       const unsigned long long* __restrict__ packed,
                       float* __restrict__ out, float* __restrict__ partial, int V) {
    __shared__ float red[TPB];
    int n = blockIdx.x * TPB + threadIdx.x;
    int b = n >> 10, hw = n & 1023;
    unsigned long long p = packed[n];
    int idx = (V - 1) - (int)(unsigned int)(p & 0xFFFFFFFFull);

    float zrow[ZC];
    float s = 0.f;
#pragma unroll
    for (int c = 0; c < ZC; ++c) {
        float t = z[((size_t)b * ZC + c) * HW + hw];
        zrow[c] = t;
        s += t * t;
    }
    float inv = 1.0f / fmaxf(sqrtf(s), 1e-12f);

    const float4* er = reinterpret_cast<const float4*>(e) + (size_t)idx * 8;
    float loss = 0.f;
#pragma unroll
    for (int q = 0; q < 8; ++q) {
        float4 ev = er[q];
        float d0 = ev.x - zrow[4 * q + 0] * inv;
        float d1 = ev.y - zrow[4 * q + 1] * inv;
        float d2 = ev.z - zrow[4 * q + 2] * inv;
        float d3 = ev.w - zrow[4 * q + 3] * inv;
        loss += d0 * d0 + d1 * d1 + d2 * d2 + d3 * d3;
        out[((size_t)b * ZC + (4 * q + 0)) * HW + hw] = ev.x;
        out[((size_t)b * ZC + (4 * q + 1)) * HW + hw] = ev.y;
        out[((size_t)b * ZC + (4 * q + 2)) * HW + hw] = ev.z;
        out[((size_t)b * ZC + (4 * q + 3)) * HW + hw] = ev.w;
    }

    red[threadIdx.x] = loss;
    __syncthreads();
    for (int st = TPB / 2; st > 0; st >>= 1) {
        if (threadIdx.x < st) red[threadIdx.x] += red[threadIdx.x + st];
        __syncthreads();
    }
    if (threadIdx.x == 0) partial[blockIdx.x] = red[0];
}

// Loss: one-wave shuffle tree over the 64 block partials (deterministic order).
__global__ void kloss(const float* __restrict__ partial, float* __restrict__ out,
                      int nblocks, int NC) {
    int lane = threadIdx.x;
    float s = (lane < nblocks) ? partial[lane] : 0.f;
#pragma unroll
    for (int off = 32; off > 0; off >>= 1) s += __shfl_down(s, off);
    if (lane == 0) {
        float mean = s / (float)NC;
        out[NC] = mean;             // vq_loss
        out[NC + 1] = 0.25f * mean; // commit_loss (BETA = 0.25)
    }
}

extern "C" void kernel_launch(void* const* d_in, const int* in_sizes, int n_in,
                              void* d_out, int out_size, void* d_ws, size_t ws_size,
                              hipStream_t stream) {
    const float* z = (const float*)d_in[0];
    const float* emb = (const float*)d_in[1];
    float* out = (float*)d_out;

    const int N = in_sizes[0] / ZC;   // 16384
    const int V = in_sizes[1] / ZC;   // 8192

    // workspace layout (all 16B-aligned)
    char* ws = (char*)d_ws;
    float* e = (float*)ws;                                   // V*32 f32   = 1 MB
    f16* Eh = (f16*)(ws + (size_t)V * ZC * 4);               // 0.5 MB
    f16* El = (f16*)(ws + (size_t)V * ZC * 6);               // 0.5 MB
    f16x8* ZFh = (f16x8*)(ws + (size_t)V * ZC * 8);          // 1 MB
    f16x8* ZFl = (f16x8*)(ws + (size_t)V * ZC * 8 + (size_t)N * ZC * 2);
    unsigned long long* packed =
        (unsigned long long*)(ws + (size_t)V * ZC * 8 + (size_t)N * ZC * 4);
    float* partial = (float*)((char*)packed + (size_t)N * 8);

    const int zblocks = (N * 4 + TPB - 1) / TPB;   // 256
    const int eblocks = (V + TPB - 1) / TPB;       // 32

    kprep<<<zblocks + eblocks, TPB, 0, stream>>>(z, emb, e, Eh, El, ZFh, ZFl,
                                                 packed, N, V, zblocks);
    kmfma<<<(V / VCH) * (N / ZROWS_BLK), TPB, 0, stream>>>(
        ZFh, ZFl, (const uint4*)Eh, (const uint4*)El, packed, V - 1);
    kfinal<<<N / TPB, TPB, 0, stream>>>(z, e, packed, out, partial, V);
    kloss<<<1, 64, 0, stream>>>(partial, out, N / TPB, N * ZC);
}